// Round 1
// 295.200 us; speedup vs baseline: 1.0215x; 1.0215x over previous
//
#include <hip/hip_runtime.h>

#define TSTEPS 365
#define BGRID  20000
#define NMUL   4
#define NEARZERO 1e-6f
#define PF 4            // prefetch ring depth (shared by both chains)
#define V  2            // independent HBV chains per thread: cells (b,k) and (b,k+2)

struct F3 { float p, t, pet; };   // 12B, innermost (.,3) layout

// lanes 2i/2i+1 share b. quad_perm(1,0,3,2) swaps pair partners (0<->1, 2<->3).
__device__ __forceinline__ float pair_swap(float x) {
    int a = __builtin_amdgcn_update_dpp(0, __float_as_int(x),
                                        0xB1 /*quad_perm(1,0,3,2)*/, 0xF, 0xF, true);
    return __int_as_float(a);
}

// raw transcendentals: bare v_log_f32 / v_exp_f32, no denormal-guard codegen.
// Domain: log input >= 1e-6 (normal); exp2 input in [-120, 0] (normal).
__device__ __forceinline__ float fast_log2(float x) { return __builtin_amdgcn_logf(x); }
__device__ __forceinline__ float fast_exp2(float x) { return __builtin_amdgcn_exp2f(x); }

// thread = b*2 + khalf, khalf in {0,1}; chain v handles k = khalf + 2v.
// 40000 threads = 625 waves (0.61/SIMD): latency-bound regime -> trade wave
// count for ILP-2 inside the wave. Both chains share forcing load + ring +
// walked pointers. waves_per_eu(1,2): only 1 wave/SIMD is supplied, give RA
// a relaxed budget.
__global__ __launch_bounds__(64) __attribute__((amdgpu_waves_per_eu(1, 2)))
void hbv_fwd(
    const float* __restrict__ forcing,   // (T, B, 3)
    const float* __restrict__ pBETA,  const float* __restrict__ pFC,
    const float* __restrict__ pK0,    const float* __restrict__ pK1,
    const float* __restrict__ pK2,    const float* __restrict__ pLP,
    const float* __restrict__ pPERC,  const float* __restrict__ pUZL,
    const float* __restrict__ pTT,    const float* __restrict__ pCFMAX,
    const float* __restrict__ pCFR,   const float* __restrict__ pCWH,
    const float* __restrict__ pBETAET,const float* __restrict__ pC,
    float* __restrict__ out_avg,         // (T, B)
    float* __restrict__ out_q)           // (T, B, NMUL)
{
    const int tid = blockIdx.x * 64 + threadIdx.x;   // grid exact: 625*64 = 40000
    const int b  = tid >> 1;
    const int c0 = (b << 2) + (tid & 1);             // chain v at cell c0 + 2v

    float parBETA[V], parFC[V], parK0[V], parK1[V], parK2[V], parPERC[V],
          parUZL[V], parTT[V], parCFMAX[V], parCWH[V], parBETAET[V], parC[V],
          refreeze_coef[V], inv_FC[V], inv_LPFC[V];
#pragma unroll
    for (int v = 0; v < V; ++v) {
        const int c = c0 + 2 * v;
        parBETA[v]   = pBETA[c];   parFC[v]   = pFC[c];
        parK0[v]     = pK0[c];     parK1[v]   = pK1[c];
        parK2[v]     = pK2[c];     parPERC[v] = pPERC[c];
        parUZL[v]    = pUZL[c];    parTT[v]   = pTT[c];
        parCFMAX[v]  = pCFMAX[c];  parCWH[v]  = pCWH[c];
        parBETAET[v] = pBETAET[c]; parC[v]    = pC[c];
        refreeze_coef[v] = pCFR[c] * parCFMAX[v];
        inv_FC[v]   = 1.0f / parFC[v];
        inv_LPFC[v] = 1.0f / (pLP[c] * parFC[v]);
    }

    float snow[V], melt[V], sm[V], suz[V], slz[V];
#pragma unroll
    for (int v = 0; v < V; ++v) {
        snow[v] = NEARZERO; melt[v] = 0.0f; sm[v] = 0.0f; suz[v] = 0.0f; slz[v] = 0.0f;
    }

    // walked 64-bit pointers (2-instr add/addc per step each) — shared by both
    // chains; the v=1 q-store is the same address register + offset:8.
    const F3* __restrict__ fp = (const F3*)forcing + b;   // stride BGRID per t
    float* __restrict__ qq = out_q + c0;                   // stride BGRID*NMUL
    float* __restrict__ qa = out_avg + b;                  // stride BGRID

    // --- fill prefetch ring (one ring: forcing is shared per b) -------------
    F3 buf[PF];
#pragma unroll
    for (int i = 0; i < PF; ++i) { buf[i] = *fp; fp += BGRID; }
    // fp now points at t = PF

    auto step = [&](const F3 fv) {
        float q[V];
#pragma unroll
        for (int v = 0; v < V; ++v) {
            // snow module
            const float temp_diff = fv.t - parTT[v];
            const bool  is_rain = temp_diff > 0.0f;
            const float rain       = is_rain ? fv.p : 0.0f;
            const float snow_input = is_rain ? 0.0f : fv.p;
            float snow1 = snow[v] + snow_input;
            const float pot_melt = parCFMAX[v] * fmaxf(temp_diff, 0.0f);
            const float melt_amount = fminf(pot_melt, snow1);
            snow1 -= melt_amount;
            float melt1 = melt[v] + melt_amount;
            const float pot_refreeze = refreeze_coef[v] * fmaxf(-temp_diff, 0.0f);
            const float refreeze = fminf(pot_refreeze, melt1);
            snow[v] = snow1 + refreeze;
            melt1 -= refreeze;
            const float tosoil = fmaxf(melt1 - parCWH[v] * snow[v], 0.0f);
            melt[v] = melt1 - tosoil;

            // soil module (raw v_log/v_exp; exp2 >= 0 so no lower clamp on pow;
            // sm1 >= 0 by construction so no lower clamp on ef1)
            const float x1 = fmaxf(sm[v] * inv_FC[v], NEARZERO);
            const float soil_wet = fminf(fast_exp2(parBETA[v] * fast_log2(x1)), 1.0f);
            const float rt = rain + tosoil;
            const float recharge = rt * soil_wet;
            float sm1 = sm[v] + rt - recharge;
            const float excess = fmaxf(sm1 - parFC[v], 0.0f);
            sm1 -= excess;
            const float ef1 = fminf(sm1 * inv_LPFC[v], 1.0f);
            const float x2 = fmaxf(ef1, NEARZERO);
            const float evapfactor = fminf(fast_exp2(parBETAET[v] * fast_log2(x2)), 1.0f);
            const float etact = fminf(fv.pet * evapfactor, sm1);
            const float sm_ae = fmaxf(sm1 - etact, NEARZERO);
            const float sm_ratio = fminf(sm_ae * inv_FC[v], 1.0f);
            const float capillary = fminf(slz[v], parC[v] * slz[v] * (1.0f - sm_ratio));
            sm[v] = fmaxf(sm_ae + capillary, NEARZERO);
            float slz1 = fmaxf(slz[v] - capillary, NEARZERO);

            // response routine
            float suz1 = suz[v] + recharge + excess;
            const float perc_flux = fminf(suz1, parPERC[v]);
            suz1 -= perc_flux;
            slz1 += perc_flux;
            const float q0 = parK0[v] * fmaxf(suz1 - parUZL[v], 0.0f);
            suz1 -= q0;
            const float q1 = parK1[v] * suz1;
            suz[v] = suz1 - q1;
            const float q2 = parK2[v] * slz1;
            slz[v] = slz1 - q2;
            q[v] = q0 + q1 + q2;
        }

        qq[0] = q[0];              // k
        qq[2] = q[1];              // k+2 (same addr reg, offset:8)
        qq += BGRID * NMUL;
        // nmul mean: per-lane (k + k+2), then DPP pair-swap adds the partner
        // lane's (k' + k'+2); both pair lanes store the identical mean.
        const float h  = q[0] + q[1];
        const float qs = h + pair_swap(h);
        *qa = qs * 0.25f;
        qa += BGRID;
    };

    // --- main: full chunks of PF=4, prefetch always in range (no predicate).
    constexpr int MAINC = ((TSTEPS - PF) / PF) * PF;  // 360 -> bases 0..356
#pragma clang loop unroll(disable)
    for (int base = 0; base < MAINC; base += PF) {
#pragma unroll
        for (int j = 0; j < PF; ++j) {
            const F3 fv = buf[j];
            buf[j] = *fp; fp += BGRID;          // prefetch t+PF
            step(fv);
        }
    }
    // ring holds t = 360..363; fp at t=364
#pragma unroll
    for (int j = 0; j < PF; ++j) {
        const F3 fv = buf[j];
        if (j < TSTEPS - MAINC - PF) { buf[j] = *fp; fp += BGRID; }
        step(fv);
    }
#pragma unroll
    for (int j = 0; j < TSTEPS - MAINC - PF; ++j) {   // final step from ring
        step(buf[j]);
    }
}

extern "C" void kernel_launch(void* const* d_in, const int* in_sizes, int n_in,
                              void* d_out, int out_size, void* d_ws, size_t ws_size,
                              hipStream_t stream) {
    // inputs (fp32): 0 forcing, 1 parBETA, 2 parFC, 3 parK0, 4 parK1, 5 parK2,
    // 6 parLP, 7 parPERC, 8 parUZL, 9 parTT, 10 parCFMAX, 11 parCFR, 12 parCWH,
    // 13 parBETAET, 14 parC
    const float* forcing = (const float*)d_in[0];

    float* out_avg = (float*)d_out;                          // (T, B)
    float* out_q   = out_avg + (size_t)TSTEPS * BGRID;       // (T, B, NMUL)

    const int total = BGRID * NMUL / V;  // 40000 threads, 2 cells each
    const int block = 64;                // single-wave workgroups
    const int grid  = total / block;     // exact: 625
    hbv_fwd<<<grid, block, 0, stream>>>(forcing,
        (const float*)d_in[1], (const float*)d_in[2], (const float*)d_in[3],
        (const float*)d_in[4], (const float*)d_in[5], (const float*)d_in[6],
        (const float*)d_in[7], (const float*)d_in[8], (const float*)d_in[9],
        (const float*)d_in[10], (const float*)d_in[11], (const float*)d_in[12],
        (const float*)d_in[13], (const float*)d_in[14],
        out_avg, out_q);
}

// Round 2
// 286.162 us; speedup vs baseline: 1.0537x; 1.0316x over previous
//
#include <hip/hip_runtime.h>

#define TSTEPS 365
#define BGRID  20000
#define NMUL   4
#define NEARZERO 1e-6f
#define C    8              // steps per chunk (VMEM window: 4 ops/step * 2 chunks = 56 < 63 vmcnt max)
#define V    2              // independent HBV chains per thread: cells (b,k) and (b,k+2)
#define NCH  (TSTEPS / C)   // 45 full chunks
#define TAIL (TSTEPS - NCH * C)  // 5

struct F3 { float p, t, pet; };   // 12B, innermost (.,3) layout

// lanes 2i/2i+1 share b. quad_perm(1,0,3,2) swaps pair partners (0<->1, 2<->3).
__device__ __forceinline__ float pair_swap(float x) {
    int a = __builtin_amdgcn_update_dpp(0, __float_as_int(x),
                                        0xB1 /*quad_perm(1,0,3,2)*/, 0xF, 0xF, true);
    return __int_as_float(a);
}

// raw transcendentals: bare v_log_f32 / v_exp_f32, no denormal-guard codegen.
// Domain: log input >= 1e-6 (normal); exp2 input in [-120, 0] (normal).
__device__ __forceinline__ float fast_log2(float x) { return __builtin_amdgcn_logf(x); }
__device__ __forceinline__ float fast_exp2(float x) { return __builtin_amdgcn_exp2f(x); }

// Phase-separated chunk pipeline:
//   LOAD(next chunk) ; STORE(prev chunk results) ; COMPUTE(current chunk)
// Store-data regs are overwritten one full chunk (~2400 cyc) after issue, and
// loads are consumed one full chunk after issue -> counted vmcnt waits instead
// of the per-step store-completion drain that pinned rounds 0/1 at ~800 cyc/step.
#define LOAD_CHUNK(BUF, N)                                                  \
    _Pragma("unroll")                                                       \
    for (int j_ = 0; j_ < (N); ++j_) { BUF[j_] = *fp; fp += BGRID; }

#define STORE_CHUNK(QS, N)                                                  \
    _Pragma("unroll")                                                       \
    for (int j_ = 0; j_ < (N); ++j_) {                                      \
        qq[0] = QS[j_][0]; qq[2] = QS[j_][1]; qq += BGRID * NMUL;           \
        const float h_ = QS[j_][0] + QS[j_][1];                             \
        *qa = (h_ + pair_swap(h_)) * 0.25f; qa += BGRID;                    \
    }

#define COMPUTE_CHUNK(BUF, QO, N)                                           \
    _Pragma("unroll")                                                       \
    for (int j_ = 0; j_ < (N); ++j_) { step(BUF[j_], QO[j_]); }

// thread = b*2 + khalf, khalf in {0,1}; chain v handles k = khalf + 2v.
__global__ __launch_bounds__(64) __attribute__((amdgpu_waves_per_eu(1, 2)))
void hbv_fwd(
    const float* __restrict__ forcing,   // (T, B, 3)
    const float* __restrict__ pBETA,  const float* __restrict__ pFC,
    const float* __restrict__ pK0,    const float* __restrict__ pK1,
    const float* __restrict__ pK2,    const float* __restrict__ pLP,
    const float* __restrict__ pPERC,  const float* __restrict__ pUZL,
    const float* __restrict__ pTT,    const float* __restrict__ pCFMAX,
    const float* __restrict__ pCFR,   const float* __restrict__ pCWH,
    const float* __restrict__ pBETAET,const float* __restrict__ pC,
    float* __restrict__ out_avg,         // (T, B)
    float* __restrict__ out_q)           // (T, B, NMUL)
{
    const int tid = blockIdx.x * 64 + threadIdx.x;   // grid exact: 625*64 = 40000
    const int b  = tid >> 1;
    const int c0 = (b << 2) + (tid & 1);             // chain v at cell c0 + 2v

    float parBETA[V], parFC[V], parK0[V], parK1[V], parK2[V], parPERC[V],
          parUZL[V], parTT[V], parCFMAX[V], parCWH[V], parBETAET[V], parC[V],
          refreeze_coef[V], inv_FC[V], inv_LPFC[V];
#pragma unroll
    for (int v = 0; v < V; ++v) {
        const int c = c0 + 2 * v;
        parBETA[v]   = pBETA[c];   parFC[v]   = pFC[c];
        parK0[v]     = pK0[c];     parK1[v]   = pK1[c];
        parK2[v]     = pK2[c];     parPERC[v] = pPERC[c];
        parUZL[v]    = pUZL[c];    parTT[v]   = pTT[c];
        parCFMAX[v]  = pCFMAX[c];  parCWH[v]  = pCWH[c];
        parBETAET[v] = pBETAET[c]; parC[v]    = pC[c];
        refreeze_coef[v] = pCFR[c] * parCFMAX[v];
        inv_FC[v]   = 1.0f / parFC[v];
        inv_LPFC[v] = 1.0f / (pLP[c] * parFC[v]);
    }

    float snow[V], melt[V], sm[V], suz[V], slz[V];
#pragma unroll
    for (int v = 0; v < V; ++v) {
        snow[v] = NEARZERO; melt[v] = 0.0f; sm[v] = 0.0f; suz[v] = 0.0f; slz[v] = 0.0f;
    }

    // walked 64-bit pointers, shared by both chains; the v=1 q-store is the
    // same address register + offset:8.
    const F3* __restrict__ fp = (const F3*)forcing + b;   // stride BGRID per t
    float* __restrict__ qq = out_q + c0;                   // stride BGRID*NMUL
    float* __restrict__ qa = out_avg + b;                  // stride BGRID

    auto step = [&](const F3 fv, float (&qo)[V]) {
#pragma unroll
        for (int v = 0; v < V; ++v) {
            // snow module
            const float temp_diff = fv.t - parTT[v];
            const bool  is_rain = temp_diff > 0.0f;
            const float rain       = is_rain ? fv.p : 0.0f;
            const float snow_input = is_rain ? 0.0f : fv.p;
            float snow1 = snow[v] + snow_input;
            const float pot_melt = parCFMAX[v] * fmaxf(temp_diff, 0.0f);
            const float melt_amount = fminf(pot_melt, snow1);
            snow1 -= melt_amount;
            float melt1 = melt[v] + melt_amount;
            const float pot_refreeze = refreeze_coef[v] * fmaxf(-temp_diff, 0.0f);
            const float refreeze = fminf(pot_refreeze, melt1);
            snow[v] = snow1 + refreeze;
            melt1 -= refreeze;
            const float tosoil = fmaxf(melt1 - parCWH[v] * snow[v], 0.0f);
            melt[v] = melt1 - tosoil;

            // soil module (raw v_log/v_exp; exp2 >= 0 so no lower clamp on pow;
            // sm1 >= 0 by construction so no lower clamp on ef1)
            const float x1 = fmaxf(sm[v] * inv_FC[v], NEARZERO);
            const float soil_wet = fminf(fast_exp2(parBETA[v] * fast_log2(x1)), 1.0f);
            const float rt = rain + tosoil;
            const float recharge = rt * soil_wet;
            float sm1 = sm[v] + rt - recharge;
            const float excess = fmaxf(sm1 - parFC[v], 0.0f);
            sm1 -= excess;
            const float ef1 = fminf(sm1 * inv_LPFC[v], 1.0f);
            const float x2 = fmaxf(ef1, NEARZERO);
            const float evapfactor = fminf(fast_exp2(parBETAET[v] * fast_log2(x2)), 1.0f);
            const float etact = fminf(fv.pet * evapfactor, sm1);
            const float sm_ae = fmaxf(sm1 - etact, NEARZERO);
            const float sm_ratio = fminf(sm_ae * inv_FC[v], 1.0f);
            const float capillary = fminf(slz[v], parC[v] * slz[v] * (1.0f - sm_ratio));
            sm[v] = fmaxf(sm_ae + capillary, NEARZERO);
            float slz1 = fmaxf(slz[v] - capillary, NEARZERO);

            // response routine
            float suz1 = suz[v] + recharge + excess;
            const float perc_flux = fminf(suz1, parPERC[v]);
            suz1 -= perc_flux;
            slz1 += perc_flux;
            const float q0 = parK0[v] * fmaxf(suz1 - parUZL[v], 0.0f);
            suz1 -= q0;
            const float q1 = parK1[v] * suz1;
            suz[v] = suz1 - q1;
            const float q2 = parK2[v] * slz1;
            slz[v] = slz1 - q2;
            qo[v] = q0 + q1 + q2;
        }
    };

    // ---- software pipeline over 45 full chunks + 5-step tail ----------------
    F3 fA[C], fB[C];
    float qA[C][V], qB[C][V];

    LOAD_CHUNK(fA, C);                 // ch0 -> fA

    // chunk 0: prefetch ch1, compute ch0 (nothing to store yet)
    LOAD_CHUNK(fB, C);
    COMPUTE_CHUNK(fA, qA, C);

    // chunks 1..42 as 21 A/B pairs (buffer parity static -> no runtime indexing)
#pragma clang loop unroll(disable)
    for (int p = 0; p < 21; ++p) {
        LOAD_CHUNK(fA, C);             // ch 2p+2
        STORE_CHUNK(qA, C);            // results of ch 2p
        COMPUTE_CHUNK(fB, qB, C);      // ch 2p+1
        LOAD_CHUNK(fB, C);             // ch 2p+3
        STORE_CHUNK(qB, C);            // results of ch 2p+1
        COMPUTE_CHUNK(fA, qA, C);      // ch 2p+2
    }
    // here: qA = ch42, qB = ch41 (stored), fB = ch43; stored through ch41
    LOAD_CHUNK(fA, C);                 // ch44
    STORE_CHUNK(qA, C);                // ch42
    COMPUTE_CHUNK(fB, qB, C);          // ch43
    LOAD_CHUNK(fB, TAIL);              // ch45 (5 steps: t=360..364)
    STORE_CHUNK(qB, C);                // ch43
    COMPUTE_CHUNK(fA, qA, C);          // ch44
    STORE_CHUNK(qA, C);                // ch44
    COMPUTE_CHUNK(fB, qB, TAIL);       // ch45
    STORE_CHUNK(qB, TAIL);             // ch45 (s_endpgm drains)
}

extern "C" void kernel_launch(void* const* d_in, const int* in_sizes, int n_in,
                              void* d_out, int out_size, void* d_ws, size_t ws_size,
                              hipStream_t stream) {
    // inputs (fp32): 0 forcing, 1 parBETA, 2 parFC, 3 parK0, 4 parK1, 5 parK2,
    // 6 parLP, 7 parPERC, 8 parUZL, 9 parTT, 10 parCFMAX, 11 parCFR, 12 parCWH,
    // 13 parBETAET, 14 parC
    const float* forcing = (const float*)d_in[0];

    float* out_avg = (float*)d_out;                          // (T, B)
    float* out_q   = out_avg + (size_t)TSTEPS * BGRID;       // (T, B, NMUL)

    const int total = BGRID * NMUL / V;  // 40000 threads, 2 cells each
    const int block = 64;                // single-wave workgroups
    const int grid  = total / block;     // exact: 625
    hbv_fwd<<<grid, block, 0, stream>>>(forcing,
        (const float*)d_in[1], (const float*)d_in[2], (const float*)d_in[3],
        (const float*)d_in[4], (const float*)d_in[5], (const float*)d_in[6],
        (const float*)d_in[7], (const float*)d_in[8], (const float*)d_in[9],
        (const float*)d_in[10], (const float*)d_in[11], (const float*)d_in[12],
        (const float*)d_in[13], (const float*)d_in[14],
        out_avg, out_q);
}

// Round 3
// 285.292 us; speedup vs baseline: 1.0569x; 1.0030x over previous
//
#include <hip/hip_runtime.h>

#define TSTEPS 365
#define BGRID  20000
#define NMUL   4
#define NEARZERO 1e-6f
#define C    8              // steps per chunk
#define NCH  (TSTEPS / C)   // 45 full chunks
#define TAIL (TSTEPS - NCH * C)  // 5

struct F3 { float p, t, pet; };   // 12B, innermost (.,3) layout

// Two HBV chains per thread, packed as {x,y}. Straight-line isomorphic f32
// pairs -> SLP vectorizer -> v_pk_add/mul/fma_f32 (full-rate VOP3P on gfx950).
// min/max/select/trans have no packed form: scalar per half (subreg, no movs).
struct f2 { float x, y; };
__device__ __forceinline__ f2 operator+(f2 a, f2 b) { return {a.x + b.x, a.y + b.y}; }
__device__ __forceinline__ f2 operator-(f2 a, f2 b) { return {a.x - b.x, a.y - b.y}; }
__device__ __forceinline__ f2 operator*(f2 a, f2 b) { return {a.x * b.x, a.y * b.y}; }
__device__ __forceinline__ f2 f2min (f2 a, f2 b)   { return {fminf(a.x,b.x), fminf(a.y,b.y)}; }
__device__ __forceinline__ f2 f2max0(f2 a)         { return {fmaxf(a.x,0.f), fmaxf(a.y,0.f)}; }
__device__ __forceinline__ f2 f2maxs(f2 a, float s){ return {fmaxf(a.x,s), fmaxf(a.y,s)}; }
__device__ __forceinline__ f2 f2mins(f2 a, float s){ return {fminf(a.x,s), fminf(a.y,s)}; }

// lanes 2i/2i+1 share b. quad_perm(1,0,3,2) swaps pair partners (0<->1, 2<->3).
__device__ __forceinline__ float pair_swap(float x) {
    int a = __builtin_amdgcn_update_dpp(0, __float_as_int(x),
                                        0xB1 /*quad_perm(1,0,3,2)*/, 0xF, 0xF, true);
    return __int_as_float(a);
}

// raw transcendentals: bare v_log_f32 / v_exp_f32 (domain: log in >= 1e-6,
// exp2 in [-120, 0] — all normal, no guard codegen).
__device__ __forceinline__ float fast_log2(float x) { return __builtin_amdgcn_logf(x); }
__device__ __forceinline__ float fast_exp2(float x) { return __builtin_amdgcn_exp2f(x); }
// pow(x,e) clamped to <=1, per half (trans units are scalar-only)
__device__ __forceinline__ f2 f2pow1(f2 xv, f2 e) {
    f2 l = { fast_log2(xv.x), fast_log2(xv.y) };
    f2 m = e * l;                                   // packs
    return { fminf(fast_exp2(m.x), 1.0f), fminf(fast_exp2(m.y), 1.0f) };
}

__device__ __forceinline__ f2 ld2(const float* p, int i) {
    return *reinterpret_cast<const f2*>(p + i);     // i even -> 8B aligned
}

// Phase-separated chunk pipeline (round 2 structure, kept):
//   LOAD(next chunk) ; STORE(prev chunk results) ; COMPUTE(current chunk)
#define LOAD_CHUNK(BUF, N)                                                  \
    _Pragma("unroll")                                                       \
    for (int j_ = 0; j_ < (N); ++j_) { BUF[j_] = *fp; fp += BGRID; }

#define STORE_CHUNK(QS, N)                                                  \
    _Pragma("unroll")                                                       \
    for (int j_ = 0; j_ < (N); ++j_) {                                      \
        *qf = QS[j_]; qf += BGRID * 2;    /* one dwordx2: adjacent k pair */ \
        const float h_ = QS[j_].x + QS[j_].y;                               \
        *qa = (h_ + pair_swap(h_)) * 0.25f; qa += BGRID;                    \
    }

#define COMPUTE_CHUNK(BUF, QO, N)                                           \
    _Pragma("unroll")                                                       \
    for (int j_ = 0; j_ < (N); ++j_) { step(BUF[j_], QO[j_]); }

// thread = b*2 + khalf; this thread's cells are ADJACENT: k = 2*khalf + {0,1}
// (c0 = tid*2) -> q-store is one 8B dwordx2, params load as dwordx2.
__global__ __launch_bounds__(64) __attribute__((amdgpu_waves_per_eu(1, 2)))
void hbv_fwd(
    const float* __restrict__ forcing,   // (T, B, 3)
    const float* __restrict__ pBETA,  const float* __restrict__ pFC,
    const float* __restrict__ pK0,    const float* __restrict__ pK1,
    const float* __restrict__ pK2,    const float* __restrict__ pLP,
    const float* __restrict__ pPERC,  const float* __restrict__ pUZL,
    const float* __restrict__ pTT,    const float* __restrict__ pCFMAX,
    const float* __restrict__ pCFR,   const float* __restrict__ pCWH,
    const float* __restrict__ pBETAET,const float* __restrict__ pC,
    float* __restrict__ out_avg,         // (T, B)
    float* __restrict__ out_q)           // (T, B, NMUL)
{
    const int tid = blockIdx.x * 64 + threadIdx.x;   // grid exact: 625*64 = 40000
    const int b  = tid >> 1;
    const int c0 = tid * 2;                          // = b*4 + 2*khalf

    const f2 parBETA   = ld2(pBETA, c0);
    const f2 parFC     = ld2(pFC, c0);
    const f2 parK0     = ld2(pK0, c0);
    const f2 parK1     = ld2(pK1, c0);
    const f2 parK2     = ld2(pK2, c0);
    const f2 parLP     = ld2(pLP, c0);
    const f2 parPERC   = ld2(pPERC, c0);
    const f2 parUZL    = ld2(pUZL, c0);
    const f2 parTT     = ld2(pTT, c0);
    const f2 parCFMAX  = ld2(pCFMAX, c0);
    const f2 parCFR    = ld2(pCFR, c0);
    const f2 parCWH    = ld2(pCWH, c0);
    const f2 parBETAET = ld2(pBETAET, c0);
    const f2 parC      = ld2(pC, c0);

    const f2 refreeze_coef = parCFR * parCFMAX;
    const f2 inv_FC   = { 1.0f / parFC.x, 1.0f / parFC.y };
    const f2 inv_LPFC = { 1.0f / (parLP.x * parFC.x), 1.0f / (parLP.y * parFC.y) };

    f2 snow = {NEARZERO, NEARZERO}, melt = {0,0}, sm = {0,0}, suz = {0,0}, slz = {0,0};

    // walked 64-bit pointers, shared by both chains
    const F3* __restrict__ fp = (const F3*)forcing + b;     // stride BGRID per t
    f2* __restrict__ qf = (f2*)(out_q + c0);                 // stride BGRID*2 f2 per t
    float* __restrict__ qa = out_avg + b;                    // stride BGRID

    auto step = [&](const F3 fv, f2 &qo) {
        // snow module
        const f2 temp_diff = { fv.t - parTT.x, fv.t - parTT.y };
        const f2 rain       = { temp_diff.x > 0.0f ? fv.p : 0.0f,
                                temp_diff.y > 0.0f ? fv.p : 0.0f };
        const f2 snow_input = { temp_diff.x > 0.0f ? 0.0f : fv.p,
                                temp_diff.y > 0.0f ? 0.0f : fv.p };
        f2 snow1 = snow + snow_input;
        const f2 pot_melt = parCFMAX * f2max0(temp_diff);
        const f2 melt_amount = f2min(pot_melt, snow1);
        snow1 = snow1 - melt_amount;
        f2 melt1 = melt + melt_amount;
        const f2 pot_refreeze = refreeze_coef * f2max0(f2{-temp_diff.x, -temp_diff.y});
        const f2 refreeze = f2min(pot_refreeze, melt1);
        snow = snow1 + refreeze;
        melt1 = melt1 - refreeze;
        const f2 tosoil = f2max0(melt1 - parCWH * snow);
        melt = melt1 - tosoil;

        // soil module
        const f2 x1 = f2maxs(sm * inv_FC, NEARZERO);
        const f2 soil_wet = f2pow1(x1, parBETA);
        const f2 rt = rain + tosoil;
        const f2 recharge = rt * soil_wet;
        f2 sm1 = (sm + rt) - recharge;
        const f2 excess = f2max0(sm1 - parFC);
        sm1 = sm1 - excess;
        const f2 ef1 = f2mins(sm1 * inv_LPFC, 1.0f);
        const f2 x2 = f2maxs(ef1, NEARZERO);
        const f2 evapfactor = f2pow1(x2, parBETAET);
        const f2 etact = f2min(f2{fv.pet, fv.pet} * evapfactor, sm1);
        const f2 sm_ae = f2maxs(sm1 - etact, NEARZERO);
        const f2 sm_ratio = f2mins(sm_ae * inv_FC, 1.0f);
        const f2 one_m = { 1.0f - sm_ratio.x, 1.0f - sm_ratio.y };
        const f2 capillary = f2min(slz, parC * slz * one_m);
        sm = f2maxs(sm_ae + capillary, NEARZERO);
        f2 slz1 = f2maxs(slz - capillary, NEARZERO);

        // response routine
        f2 suz1 = (suz + recharge) + excess;
        const f2 perc_flux = f2min(suz1, parPERC);
        suz1 = suz1 - perc_flux;
        slz1 = slz1 + perc_flux;
        const f2 q0 = parK0 * f2max0(suz1 - parUZL);
        suz1 = suz1 - q0;
        const f2 q1 = parK1 * suz1;
        suz = suz1 - q1;
        const f2 q2 = parK2 * slz1;
        slz = slz1 - q2;
        qo = (q0 + q1) + q2;
    };

    // ---- software pipeline over 45 full chunks + 5-step tail ----------------
    F3 fA[C], fB[C];
    f2 qA[C], qB[C];

    LOAD_CHUNK(fA, C);                 // ch0 -> fA
    LOAD_CHUNK(fB, C);                 // ch1
    COMPUTE_CHUNK(fA, qA, C);          // ch0

    // chunks as A/B pairs (static buffer parity -> no runtime indexing)
#pragma clang loop unroll(disable)
    for (int p = 0; p < 21; ++p) {
        LOAD_CHUNK(fA, C);             // ch 2p+2
        STORE_CHUNK(qA, C);            // results of ch 2p
        COMPUTE_CHUNK(fB, qB, C);      // ch 2p+1
        LOAD_CHUNK(fB, C);             // ch 2p+3
        STORE_CHUNK(qB, C);            // results of ch 2p+1
        COMPUTE_CHUNK(fA, qA, C);      // ch 2p+2
    }
    // here: qA = ch42, fB = ch43; stored through ch41
    LOAD_CHUNK(fA, C);                 // ch44
    STORE_CHUNK(qA, C);                // ch42
    COMPUTE_CHUNK(fB, qB, C);          // ch43
    LOAD_CHUNK(fB, TAIL);              // ch45 (5 steps: t=360..364)
    STORE_CHUNK(qB, C);                // ch43
    COMPUTE_CHUNK(fA, qA, C);          // ch44
    STORE_CHUNK(qA, C);                // ch44
    COMPUTE_CHUNK(fB, qB, TAIL);       // ch45
    STORE_CHUNK(qB, TAIL);             // ch45 (s_endpgm drains)
}

extern "C" void kernel_launch(void* const* d_in, const int* in_sizes, int n_in,
                              void* d_out, int out_size, void* d_ws, size_t ws_size,
                              hipStream_t stream) {
    // inputs (fp32): 0 forcing, 1 parBETA, 2 parFC, 3 parK0, 4 parK1, 5 parK2,
    // 6 parLP, 7 parPERC, 8 parUZL, 9 parTT, 10 parCFMAX, 11 parCFR, 12 parCWH,
    // 13 parBETAET, 14 parC
    const float* forcing = (const float*)d_in[0];

    float* out_avg = (float*)d_out;                          // (T, B)
    float* out_q   = out_avg + (size_t)TSTEPS * BGRID;       // (T, B, NMUL)

    const int total = BGRID * NMUL / 2;  // 40000 threads, 2 adjacent cells each
    const int block = 64;                // single-wave workgroups
    const int grid  = total / block;     // exact: 625
    hbv_fwd<<<grid, block, 0, stream>>>(forcing,
        (const float*)d_in[1], (const float*)d_in[2], (const float*)d_in[3],
        (const float*)d_in[4], (const float*)d_in[5], (const float*)d_in[6],
        (const float*)d_in[7], (const float*)d_in[8], (const float*)d_in[9],
        (const float*)d_in[10], (const float*)d_in[11], (const float*)d_in[12],
        (const float*)d_in[13], (const float*)d_in[14],
        out_avg, out_q);
}

// Round 4
// 270.751 us; speedup vs baseline: 1.1137x; 1.0537x over previous
//
#include <hip/hip_runtime.h>

#define TSTEPS 365
#define BGRID  20000
#define NMUL   4
#define NEARZERO 1e-6f
#define C    8              // steps per chunk
#define NCH  (TSTEPS / C)   // 45 full chunks
#define TAIL (TSTEPS - NCH * C)  // 5

struct F3 { float p, t, pet; };   // 12B, innermost (.,3) layout

// Two HBV chains per thread packed in a NATIVE clang vector type: arithmetic
// on v2f emits <2 x float> IR ops directly (no SLP needed) -> backend selects
// full-rate v_pk_add/mul/fma_f32 (VOP3P, gfx90a+). min/max/select/trans have
// no packed f32 form: they scalarize per half with neg/abs folded as VOP3
// source modifiers (free).
typedef float v2f __attribute__((ext_vector_type(2)));

__device__ __forceinline__ v2f v2min(v2f a, v2f b) {
    v2f r; r.x = fminf(a.x, b.x); r.y = fminf(a.y, b.y); return r;
}
__device__ __forceinline__ v2f v2max(v2f a, v2f b) {
    v2f r; r.x = fmaxf(a.x, b.x); r.y = fmaxf(a.y, b.y); return r;
}
__device__ __forceinline__ v2f v2max0(v2f a) {
    v2f r; r.x = fmaxf(a.x, 0.0f); r.y = fmaxf(a.y, 0.0f); return r;
}
__device__ __forceinline__ v2f v2maxs(v2f a, float s) {
    v2f r; r.x = fmaxf(a.x, s); r.y = fmaxf(a.y, s); return r;
}
__device__ __forceinline__ v2f v2mins(v2f a, float s) {
    v2f r; r.x = fminf(a.x, s); r.y = fminf(a.y, s); return r;
}
// clamp(x, lo, hi) in ONE v_med3_f32 per half
__device__ __forceinline__ v2f v2clamp(v2f a, float lo, float hi) {
    v2f r; r.x = __builtin_amdgcn_fmed3f(a.x, lo, hi);
           r.y = __builtin_amdgcn_fmed3f(a.y, lo, hi); return r;
}

// lanes 2i/2i+1 share b. quad_perm(1,0,3,2) swaps pair partners (0<->1, 2<->3).
__device__ __forceinline__ float pair_swap(float x) {
    int a = __builtin_amdgcn_update_dpp(0, __float_as_int(x),
                                        0xB1 /*quad_perm(1,0,3,2)*/, 0xF, 0xF, true);
    return __int_as_float(a);
}

// raw transcendentals: bare v_log_f32 / v_exp_f32 (domain: log in >= 1e-6,
// exp2 in [-120, 0] — all normal, no guard codegen).
__device__ __forceinline__ float fast_log2(float x) { return __builtin_amdgcn_logf(x); }
__device__ __forceinline__ float fast_exp2(float x) { return __builtin_amdgcn_exp2f(x); }
// pow(x,e) clamped to <=1: trans scalar per half, the e*log2 mul packs.
__device__ __forceinline__ v2f v2pow1(v2f xv, v2f e) {
    v2f l; l.x = fast_log2(xv.x); l.y = fast_log2(xv.y);
    v2f m = e * l;                                   // v_pk_mul_f32
    v2f r; r.x = fminf(fast_exp2(m.x), 1.0f); r.y = fminf(fast_exp2(m.y), 1.0f);
    return r;
}

__device__ __forceinline__ v2f ld2(const float* p, int i) {
    return *reinterpret_cast<const v2f*>(p + i);     // i even -> 8B aligned
}

// Phase-separated chunk pipeline (round 2 structure, kept):
//   LOAD(next chunk) ; STORE(prev chunk results) ; COMPUTE(current chunk)
#define LOAD_CHUNK(BUF, N)                                                  \
    _Pragma("unroll")                                                       \
    for (int j_ = 0; j_ < (N); ++j_) { BUF[j_] = *fp; fp += BGRID; }

#define STORE_CHUNK(QS, N)                                                  \
    _Pragma("unroll")                                                       \
    for (int j_ = 0; j_ < (N); ++j_) {                                      \
        *qf = QS[j_]; qf += BGRID * 2;    /* one dwordx2: adjacent k pair */ \
        const float h_ = QS[j_].x + QS[j_].y;                               \
        *qa = (h_ + pair_swap(h_)) * 0.25f; qa += BGRID;                    \
    }

#define COMPUTE_CHUNK(BUF, QO, N)                                           \
    _Pragma("unroll")                                                       \
    for (int j_ = 0; j_ < (N); ++j_) { step(BUF[j_], QO[j_]); }

// thread = b*2 + khalf; cells ADJACENT: k = 2*khalf + {0,1} (c0 = tid*2)
// -> q-store is one 8B dwordx2, params load as dwordx2.
__global__ __launch_bounds__(64) __attribute__((amdgpu_waves_per_eu(1, 2)))
void hbv_fwd(
    const float* __restrict__ forcing,   // (T, B, 3)
    const float* __restrict__ pBETA,  const float* __restrict__ pFC,
    const float* __restrict__ pK0,    const float* __restrict__ pK1,
    const float* __restrict__ pK2,    const float* __restrict__ pLP,
    const float* __restrict__ pPERC,  const float* __restrict__ pUZL,
    const float* __restrict__ pTT,    const float* __restrict__ pCFMAX,
    const float* __restrict__ pCFR,   const float* __restrict__ pCWH,
    const float* __restrict__ pBETAET,const float* __restrict__ pC,
    float* __restrict__ out_avg,         // (T, B)
    float* __restrict__ out_q)           // (T, B, NMUL)
{
    const int tid = blockIdx.x * 64 + threadIdx.x;   // grid exact: 625*64 = 40000
    const int b  = tid >> 1;
    const int c0 = tid * 2;                          // = b*4 + 2*khalf

    const v2f parBETA   = ld2(pBETA, c0);
    const v2f parFC     = ld2(pFC, c0);
    const v2f parK0     = ld2(pK0, c0);
    const v2f parK1     = ld2(pK1, c0);
    const v2f parK2     = ld2(pK2, c0);
    const v2f parLP     = ld2(pLP, c0);
    const v2f parPERC   = ld2(pPERC, c0);
    const v2f parUZL    = ld2(pUZL, c0);
    const v2f parTT     = ld2(pTT, c0);
    const v2f parCFMAX  = ld2(pCFMAX, c0);
    const v2f parCFR    = ld2(pCFR, c0);
    const v2f parCWH    = ld2(pCWH, c0);
    const v2f parBETAET = ld2(pBETAET, c0);
    const v2f parC      = ld2(pC, c0);

    const v2f refreeze_coef = parCFR * parCFMAX;
    v2f inv_FC, inv_LPFC;
    inv_FC.x   = 1.0f / parFC.x;                 inv_FC.y   = 1.0f / parFC.y;
    inv_LPFC.x = 1.0f / (parLP.x * parFC.x);     inv_LPFC.y = 1.0f / (parLP.y * parFC.y);

    v2f snow = {NEARZERO, NEARZERO}, melt = {0.f,0.f}, sm = {0.f,0.f},
        suz = {0.f,0.f}, slz = {0.f,0.f};

    // walked 64-bit pointers, shared by both chains
    const F3* __restrict__ fp = (const F3*)forcing + b;     // stride BGRID per t
    v2f* __restrict__ qf = (v2f*)(out_q + c0);               // stride BGRID*2 v2f per t
    float* __restrict__ qa = out_avg + b;                    // stride BGRID

    auto step = [&](const F3 fv, v2f &qo) {
        // snow module
        const v2f temp_diff = fv.t - parTT;          // broadcast sub -> pk
        v2f rain; rain.x = temp_diff.x > 0.0f ? fv.p : 0.0f;
                  rain.y = temp_diff.y > 0.0f ? fv.p : 0.0f;
        const v2f snow_input = fv.p - rain;          // p = rain + snow_input
        v2f snow1 = snow + snow_input;
        const v2f pot_melt = parCFMAX * v2max0(temp_diff);
        const v2f melt_amount = v2min(pot_melt, snow1);
        snow1 = snow1 - melt_amount;
        v2f melt1 = melt + melt_amount;
        const v2f pot_refreeze = refreeze_coef * v2max0(-temp_diff); // neg folds
        const v2f refreeze = v2min(pot_refreeze, melt1);
        snow = snow1 + refreeze;
        melt1 = melt1 - refreeze;
        const v2f tosoil = v2max0(melt1 - parCWH * snow);   // pk_fma + max
        melt = melt1 - tosoil;

        // soil module
        const v2f x1 = v2maxs(sm * inv_FC, NEARZERO);
        const v2f soil_wet = v2pow1(x1, parBETA);
        const v2f rt = rain + tosoil;
        const v2f recharge = rt * soil_wet;
        v2f sm1 = (sm + rt) - recharge;
        const v2f excess = v2max0(sm1 - parFC);
        sm1 = sm1 - excess;
        const v2f x2 = v2clamp(sm1 * inv_LPFC, NEARZERO, 1.0f);  // med3 per half
        const v2f evapfactor = v2pow1(x2, parBETAET);
        const v2f etact = v2min(fv.pet * evapfactor, sm1);
        const v2f sm_ae = v2maxs(sm1 - etact, NEARZERO);
        const v2f sm_ratio = v2mins(sm_ae * inv_FC, 1.0f);
        const v2f capillary = v2min(slz, parC * slz * (1.0f - sm_ratio));
        sm = v2maxs(sm_ae + capillary, NEARZERO);
        v2f slz1 = v2maxs(slz - capillary, NEARZERO);

        // response routine
        v2f suz1 = (suz + recharge) + excess;
        const v2f perc_flux = v2min(suz1, parPERC);
        suz1 = suz1 - perc_flux;
        slz1 = slz1 + perc_flux;
        const v2f q0 = parK0 * v2max0(suz1 - parUZL);
        suz1 = suz1 - q0;
        const v2f q1 = parK1 * suz1;
        suz = suz1 - q1;
        const v2f q2 = parK2 * slz1;
        slz = slz1 - q2;
        qo = (q0 + q1) + q2;
    };

    // ---- software pipeline over 45 full chunks + 5-step tail ----------------
    F3 fA[C], fB[C];
    v2f qA[C], qB[C];

    LOAD_CHUNK(fA, C);                 // ch0 -> fA
    LOAD_CHUNK(fB, C);                 // ch1
    COMPUTE_CHUNK(fA, qA, C);          // ch0

    // chunks as A/B pairs (static buffer parity -> no runtime indexing)
#pragma clang loop unroll(disable)
    for (int p = 0; p < 21; ++p) {
        LOAD_CHUNK(fA, C);             // ch 2p+2
        STORE_CHUNK(qA, C);            // results of ch 2p
        COMPUTE_CHUNK(fB, qB, C);      // ch 2p+1
        LOAD_CHUNK(fB, C);             // ch 2p+3
        STORE_CHUNK(qB, C);            // results of ch 2p+1
        COMPUTE_CHUNK(fA, qA, C);      // ch 2p+2
    }
    // here: qA = ch42, fB = ch43; stored through ch41
    LOAD_CHUNK(fA, C);                 // ch44
    STORE_CHUNK(qA, C);                // ch42
    COMPUTE_CHUNK(fB, qB, C);          // ch43
    LOAD_CHUNK(fB, TAIL);              // ch45 (5 steps: t=360..364)
    STORE_CHUNK(qB, C);                // ch43
    COMPUTE_CHUNK(fA, qA, C);          // ch44
    STORE_CHUNK(qA, C);                // ch44
    COMPUTE_CHUNK(fB, qB, TAIL);       // ch45
    STORE_CHUNK(qB, TAIL);             // ch45 (s_endpgm drains)
}

extern "C" void kernel_launch(void* const* d_in, const int* in_sizes, int n_in,
                              void* d_out, int out_size, void* d_ws, size_t ws_size,
                              hipStream_t stream) {
    // inputs (fp32): 0 forcing, 1 parBETA, 2 parFC, 3 parK0, 4 parK1, 5 parK2,
    // 6 parLP, 7 parPERC, 8 parUZL, 9 parTT, 10 parCFMAX, 11 parCFR, 12 parCWH,
    // 13 parBETAET, 14 parC
    const float* forcing = (const float*)d_in[0];

    float* out_avg = (float*)d_out;                          // (T, B)
    float* out_q   = out_avg + (size_t)TSTEPS * BGRID;       // (T, B, NMUL)

    const int total = BGRID * NMUL / 2;  // 40000 threads, 2 adjacent cells each
    const int block = 64;                // single-wave workgroups
    const int grid  = total / block;     // exact: 625
    hbv_fwd<<<grid, block, 0, stream>>>(forcing,
        (const float*)d_in[1], (const float*)d_in[2], (const float*)d_in[3],
        (const float*)d_in[4], (const float*)d_in[5], (const float*)d_in[6],
        (const float*)d_in[7], (const float*)d_in[8], (const float*)d_in[9],
        (const float*)d_in[10], (const float*)d_in[11], (const float*)d_in[12],
        (const float*)d_in[13], (const float*)d_in[14],
        out_avg, out_q);
}